// Round 1
// baseline (33.439 us; speedup 1.0000x reference)
//
#include <hip/hip_runtime.h>
#include <math.h>

#define HB 16
#define CB 64
#define HH 128
#define WW 128
// output: H2 = W2 = 128 (padding=2, stride=1, k=5)

__device__ __forceinline__ float4 ldrow(const float* __restrict__ plane, int r, int cb) {
    // cb = 4-col block index; valid iff 0<=r<128 && 0<=cb<32, else zero (padding)
    if ((unsigned)r < (unsigned)HH && (unsigned)cb < (unsigned)(WW / 4)) {
        return *reinterpret_cast<const float4*>(plane + r * WW + cb * 4);
    }
    return make_float4(0.f, 0.f, 0.f, 0.f);
}

__global__ __launch_bounds__(256) void morpho_kernel(
    const float* __restrict__ x,     // [B,C,H,W]
    const float* __restrict__ w,     // [B,C,5,5]
    const float* __restrict__ bias,  // [B,C]
    const float* __restrict__ sign,  // [B]
    float* __restrict__ out)         // [B,C,128,128]
{
    const int blk  = blockIdx.x;
    const int quad = blk & 3;        // which 32-row band
    const int bc   = blk >> 2;       // plane index = b*64 + c
    const int b    = bc >> 6;

    const float* __restrict__ xp = x   + (size_t)bc * (HH * WW);
    float*       __restrict__ yp = out + (size_t)bc * (HH * WW);
    const float* __restrict__ wp = w   + bc * 25;

    const float sgn = sign[b];
    const float s   = (fabsf(sgn) >= 1e-7f) ? sgn : 1.0f;
    const float bv  = bias[bc];

    float wv[25];
#pragma unroll
    for (int k = 0; k < 25; ++k) wv[k] = wp[k];

    const int t  = threadIdx.x;
    const int tx = t & 31;           // col-block (4 cols each)
    const int ty = t >> 5;           // 0..7
    const int j0 = tx * 4;
    const int i0 = quad * 32 + ty * 4;

    float acc[4][4];
#pragma unroll
    for (int a = 0; a < 4; ++a)
#pragma unroll
        for (int c2 = 0; c2 < 4; ++c2) acc[a][c2] = -INFINITY;

#pragma unroll
    for (int r8 = 0; r8 < 8; ++r8) {
        const int r = i0 - 2 + r8;
        float4 v0 = ldrow(xp, r, tx - 1);
        float4 v1 = ldrow(xp, r, tx);
        float4 v2 = ldrow(xp, r, tx + 1);
        float xr[12];
        xr[0] = v0.x * s;  xr[1] = v0.y * s;  xr[2]  = v0.z * s;  xr[3]  = v0.w * s;
        xr[4] = v1.x * s;  xr[5] = v1.y * s;  xr[6]  = v1.z * s;  xr[7]  = v1.w * s;
        xr[8] = v2.x * s;  xr[9] = v2.y * s;  xr[10] = v2.z * s;  xr[11] = v2.w * s;
#pragma unroll
        for (int p = 0; p < 5; ++p) {
            const int oi = r8 - p;   // output row within 4-row tile fed by this input row
            if (oi >= 0 && oi < 4) {
#pragma unroll
                for (int q = 0; q < 5; ++q) {
                    const float wq = wv[p * 5 + q];
#pragma unroll
                    for (int oj = 0; oj < 4; ++oj) {
                        // input col = j0 + oj + q - 2 -> xr index oj + q + 2 (xr starts at j0-4)
                        acc[oi][oj] = fmaxf(acc[oi][oj], xr[oj + q + 2] + wq);
                    }
                }
            }
        }
    }

#pragma unroll
    for (int a = 0; a < 4; ++a) {
        float4 o;
        o.x = (acc[a][0] + bv) * s;
        o.y = (acc[a][1] + bv) * s;
        o.z = (acc[a][2] + bv) * s;
        o.w = (acc[a][3] + bv) * s;
        *reinterpret_cast<float4*>(yp + (size_t)(i0 + a) * WW + j0) = o;
    }
}

extern "C" void kernel_launch(void* const* d_in, const int* in_sizes, int n_in,
                              void* d_out, int out_size, void* d_ws, size_t ws_size,
                              hipStream_t stream) {
    const float* x    = (const float*)d_in[0];
    const float* w    = (const float*)d_in[1];
    const float* bias = (const float*)d_in[2];
    const float* sign = (const float*)d_in[3];
    float* out = (float*)d_out;

    const int planes = HB * CB;          // 1024
    const int grid   = planes * 4;       // 4 row-bands per plane
    morpho_kernel<<<grid, 256, 0, stream>>>(x, w, bias, sign, out);
}

// Round 2
// 32.171 us; speedup vs baseline: 1.0394x; 1.0394x over previous
//
#include <hip/hip_runtime.h>
#include <math.h>

#define HB 16
#define CB 64
#define HH 128
#define WW 128
#define NFLOATS (HB * CB * HH * WW)   // 16,777,216

__global__ __launch_bounds__(256) void morpho_kernel(
    const float* __restrict__ x,     // [B,C,128,128]
    const float* __restrict__ w,     // [B,C,5,5]
    const float* __restrict__ bias,  // [B,C]
    const float* __restrict__ sign,  // [B]
    float* __restrict__ out)         // [B,C,128,128]
{
    const int blk  = blockIdx.x;
    const int quad = blk & 3;        // 32-row band
    const int bc   = blk >> 2;       // plane = b*64 + c
    const int b    = bc >> 6;

    float*       __restrict__ yp = out + (size_t)bc * (HH * WW);
    const float* __restrict__ wp = w   + bc * 25;

    const float sgn = sign[b];
    const float s   = (fabsf(sgn) >= 1e-7f) ? sgn : 1.0f;
    const float bv  = bias[bc];

    float wv[25];
#pragma unroll
    for (int k = 0; k < 25; ++k) wv[k] = wp[k];

    const int t  = threadIdx.x;
    const int tx = t & 31;           // col-block (4 cols)
    const int ty = t >> 5;           // 0..7
    const int j0 = tx * 4;
    const int i0 = quad * 32 + ty * 4;

    // thread-constant effective scales for left/right halo blocks (col padding)
    const float sL = (tx >= 1)  ? s : 0.f;
    const float sR = (tx <= 30) ? s : 0.f;

    const int planeOff = bc * (HH * WW);

    float acc[4][4];                 // first-touch initialized at p==0

#pragma unroll
    for (int r8 = 0; r8 < 8; ++r8) {
        const int r  = i0 - 2 + r8;
        const bool rv = ((unsigned)r < (unsigned)HH);   // row padding
        const float smM = rv ? s  : 0.f;
        const float smL = rv ? sL : 0.f;
        const float smR = rv ? sR : 0.f;

        // flat float offsets, clamped into the buffer -> unconditional loads
        int oM = planeOff + r * WW + j0;
        int oL = oM - 4;
        int oR = oM + 4;
        oL = min(max(oL, 0), NFLOATS - 4);
        oM = min(max(oM, 0), NFLOATS - 4);
        oR = min(max(oR, 0), NFLOATS - 4);

        const float4 v0 = *reinterpret_cast<const float4*>(x + oL);
        const float4 v1 = *reinterpret_cast<const float4*>(x + oM);
        const float4 v2 = *reinterpret_cast<const float4*>(x + oR);

        float xr[12];
        xr[0]  = v0.x * smL; xr[1]  = v0.y * smL; xr[2]  = v0.z * smL; xr[3]  = v0.w * smL;
        xr[4]  = v1.x * smM; xr[5]  = v1.y * smM; xr[6]  = v1.z * smM; xr[7]  = v1.w * smM;
        xr[8]  = v2.x * smR; xr[9]  = v2.y * smR; xr[10] = v2.z * smR; xr[11] = v2.w * smR;

#pragma unroll
        for (int p = 0; p < 5; ++p) {
            const int oi = r8 - p;   // output row in 4-row tile fed by this input row
            if (oi >= 0 && oi < 4) {
#pragma unroll
                for (int oj = 0; oj < 4; ++oj) {
                    // input col = j0 + oj + q - 2 -> xr index oj + q + 2
                    const float t0 = xr[oj + 2] + wv[p * 5 + 0];
                    const float t1 = xr[oj + 3] + wv[p * 5 + 1];
                    const float t2 = xr[oj + 4] + wv[p * 5 + 2];
                    const float t3 = xr[oj + 5] + wv[p * 5 + 3];
                    const float t4 = xr[oj + 6] + wv[p * 5 + 4];
                    float m;
                    if (p == 0) {
                        // first touch of this output row: no acc read
                        m = fmaxf(fmaxf(t0, t1), t2);   // -> v_max3
                        m = fmaxf(fmaxf(m, t3), t4);    // -> v_max3
                    } else {
                        m = acc[oi][oj];
                        m = fmaxf(fmaxf(m, t0), t1);    // -> v_max3
                        m = fmaxf(fmaxf(m, t2), t3);    // -> v_max3
                        m = fmaxf(m, t4);
                    }
                    acc[oi][oj] = m;
                }
            }
        }
    }

#pragma unroll
    for (int a = 0; a < 4; ++a) {
        float4 o;
        o.x = (acc[a][0] + bv) * s;
        o.y = (acc[a][1] + bv) * s;
        o.z = (acc[a][2] + bv) * s;
        o.w = (acc[a][3] + bv) * s;
        *reinterpret_cast<float4*>(yp + (size_t)(i0 + a) * WW + j0) = o;
    }
}

extern "C" void kernel_launch(void* const* d_in, const int* in_sizes, int n_in,
                              void* d_out, int out_size, void* d_ws, size_t ws_size,
                              hipStream_t stream) {
    const float* x    = (const float*)d_in[0];
    const float* w    = (const float*)d_in[1];
    const float* bias = (const float*)d_in[2];
    const float* sign = (const float*)d_in[3];
    float* out = (float*)d_out;

    const int planes = HB * CB;      // 1024
    const int grid   = planes * 4;   // 4 row-bands per plane
    morpho_kernel<<<grid, 256, 0, stream>>>(x, w, bias, sign, out);
}